// Round 2
// baseline (13344.115 us; speedup 1.0000x reference)
//
#include <hip/hip_runtime.h>
#include <math.h>

// ---------------------------------------------------------------------------
// Decoder: 3-layer LSTM (teacher forcing) + dot attention + MLP + CE loss.
// B=16, L=256, T=257, E=512, H=1024, ENC2=1024, S=512, V=1024.
//
// Workspace budget: 76.6 MB total (round-0 crash attributed to ws overflow).
//   h2 full history (epilogue needs it), h0/h1 as 4-slot rings,
//   gate partials aliased with epilogue buffers, no weight pre-transform.
// Recurrence: wavefront diagonals d = t + layer; per diagonal one fused
//   phase-1 kernel (6 NT-GEMM jobs, M=16, N=4096, K-split 4) + one update.
// ---------------------------------------------------------------------------

namespace {
constexpr int BB = 16;     // batch
constexpr int TT = 257;    // L+1
constexpr int BT = 4112;   // BB*TT

// float-element offsets into workspace
constexpr size_t OFF_H2  = 0;                      // [258][16][1024]
constexpr size_t OFF_H0R = 4227072;                // [4][16][1024] ring
constexpr size_t OFF_H1R = 4292608;                // [4][16][1024] ring
constexpr size_t OFF_C   = 4358144;                // [3][16][1024]
constexpr size_t OFF_GP  = 4407296;                // [24][16][4096] = 1572864
// epilogue aliases over GP region (GP dead after recurrence):
constexpr size_t OFF_SC  = OFF_GP;                 // [16][257][512] = 2105344
constexpr size_t OFF_CTX = OFF_SC + 2105344;       // [4112][1024]
constexpr size_t OFF_HID = OFF_CTX + 4210688;      // [4112][1024]
constexpr size_t OFF_LOG = OFF_HID + 4210688;      // [4112][1024]
constexpr size_t OFF_INT = OFF_LOG + 4210688;      // 3 x 4112 ints
constexpr size_t TOTAL_FLOATS = OFF_INT + 12336;   // 19,157,040 -> 76.6 MB
}

// ---------------------------------------------------------------------------
__global__ void k_fail(float* out) { out[0] = -123456.0f; }

// ---------------------------------------------------------------------------
__global__ __launch_bounds__(256) void k_init(const int* __restrict__ tokens,
                                              float* __restrict__ ws,
                                              float* __restrict__ out)
{
    int i = blockIdx.x * 256 + threadIdx.x;
    int* dec_in  = (int*)(ws + OFF_INT);
    int* dec_out = dec_in + 4112;
    int* hsrow   = dec_in + 8224;
    if (i < 4112) {
        int t = i >> 4, b = i & 15;                 // tb-order (t-major)
        dec_in[i] = (t == 0) ? 1 : tokens[b * 256 + (t - 1)];
        int bb = i / 257, tt = i % 257;             // m-order (b-major)
        dec_out[i] = (tt < 256) ? tokens[bb * 256 + tt] : 2;
        hsrow[i] = (tt + 1) * 16 + bb;
    }
    if (i < 3 * 16 * 1024) ws[OFF_C + i] = 0.f;
    if (i < 16 * 1024) {
        ws[OFF_H0R + i] = 0.f;                      // ring slot 0
        ws[OFF_H1R + i] = 0.f;                      // ring slot 0
        ws[OFF_H2 + i]  = 0.f;                      // history slot 0
    }
    if (i == 0) out[0] = 0.f;
}

// ---------------------------------------------------------------------------
// Phase 1: six NT gate matmuls for diagonal d, fused in one kernel.
// grid = 6 jobs x 16 n-slabs x 4 k-parts = 384 blocks of 256 threads.
// Block computes gp[job*4+kp][16 b][256 n] += over its K/4 range.
// jobs: 0 cell0-ih (emb gather, K=512)  1 cell0-hh  2 cell1-ih
//       3 cell1-hh  4 cell2-ih  5 cell2-hh
__global__ __launch_bounds__(256) void k_rec_gates(
    const float* __restrict__ emb,
    const float* __restrict__ Wih0, const float* __restrict__ Whh0,
    const float* __restrict__ Wih1, const float* __restrict__ Whh1,
    const float* __restrict__ Wih2, const float* __restrict__ Whh2,
    const float* __restrict__ h0r, const float* __restrict__ h1r,
    const float* __restrict__ h2, const int* __restrict__ dec_in,
    float* __restrict__ gp, int d)
{
    __shared__ float As[32][18];
    __shared__ float Bs[32][264];
    int bx = blockIdx.x;
    int job = bx >> 6, rem = bx & 63, ns = rem >> 2, kp = rem & 3;
    int t, lda, ldb, K4;
    const float* A; const float* B; const int* aidx = nullptr;
    if (job == 0)      { t = d;     A = emb;                              lda = 512;  B = Wih0; ldb = 1536; K4 = 128;
                         aidx = dec_in + (size_t)d * 16; }
    else if (job == 1) { t = d;     A = h0r + (size_t)(d & 3) * 16384;       lda = 1024; B = Whh0; ldb = 1024; K4 = 256; }
    else if (job == 2) { t = d - 1; A = h0r + (size_t)(d & 3) * 16384;       lda = 1024; B = Wih1; ldb = 1024; K4 = 256; }
    else if (job == 3) { t = d - 1; A = h1r + (size_t)((d - 1) & 3) * 16384; lda = 1024; B = Whh1; ldb = 1024; K4 = 256; }
    else if (job == 4) { t = d - 2; A = h1r + (size_t)((d - 1) & 3) * 16384; lda = 1024; B = Wih2; ldb = 1024; K4 = 256; }
    else               { t = d - 2; A = h2 + (size_t)(d - 2) * 16384;        lda = 1024; B = Whh2; ldb = 1024; K4 = 256; }
    if (t < 0 || t >= TT) return;
    int n0 = ns * 256, kst = kp * K4;
    int tid = threadIdx.x;
    int tx = tid & 31, ty = tid >> 5;              // n-group / m-group
    float acc[2][8] = {};
    for (int k0 = 0; k0 < K4; k0 += 32) {
        __syncthreads();
        if (tid < 128) {                            // A tile: 16 x 32
            int b = tid >> 3, kk = (tid & 7) * 4;
            const float* ar = A + (size_t)(aidx ? aidx[b] : b) * lda + kst + k0 + kk;
            float4 v = *(const float4*)ar;
            As[kk + 0][b] = v.x; As[kk + 1][b] = v.y;
            As[kk + 2][b] = v.z; As[kk + 3][b] = v.w;
        }
        #pragma unroll
        for (int it = 0; it < 8; it++) {            // B tile: 256 x 32
            int flat = tid * 4 + it * 1024;
            int n = flat >> 5, kk = flat & 31;
            float4 v = *(const float4*)(B + (size_t)(n0 + n) * ldb + kst + k0 + kk);
            Bs[kk + 0][n] = v.x; Bs[kk + 1][n] = v.y;
            Bs[kk + 2][n] = v.z; Bs[kk + 3][n] = v.w;
        }
        __syncthreads();
        #pragma unroll
        for (int k = 0; k < 32; k++) {
            float a0 = As[k][ty * 2], a1 = As[k][ty * 2 + 1];
            float4 b0 = *(const float4*)&Bs[k][tx * 8];
            float4 b1 = *(const float4*)&Bs[k][tx * 8 + 4];
            float bn[8] = {b0.x, b0.y, b0.z, b0.w, b1.x, b1.y, b1.z, b1.w};
            #pragma unroll
            for (int j = 0; j < 8; j++) {
                acc[0][j] = fmaf(a0, bn[j], acc[0][j]);
                acc[1][j] = fmaf(a1, bn[j], acc[1][j]);
            }
        }
    }
    int slot = job * 4 + kp;
    #pragma unroll
    for (int i = 0; i < 2; i++) {
        int m = ty * 2 + i;
        float* gpp = gp + ((size_t)(slot * 16 + m)) * 4096 + n0 + tx * 8;
        *(float4*)gpp       = make_float4(acc[i][0], acc[i][1], acc[i][2], acc[i][3]);
        *(float4*)(gpp + 4) = make_float4(acc[i][4], acc[i][5], acc[i][6], acc[i][7]);
    }
}

// ---------------------------------------------------------------------------
// Phase 2: sum 8 partial slices per cell, add biases, gate nonlinearities,
// c/h update. 3 cells x 64 blocks x 256 threads.
__global__ __launch_bounds__(256) void k_rec_up(
    const float* __restrict__ gp,
    const float* __restrict__ bih0, const float* __restrict__ bhh0,
    const float* __restrict__ bih1, const float* __restrict__ bhh1,
    const float* __restrict__ bih2, const float* __restrict__ bhh2,
    float* __restrict__ h0r, float* __restrict__ h1r, float* __restrict__ h2,
    float* __restrict__ cbuf, int d)
{
    int cs = blockIdx.x >> 6;
    int t = d - cs;
    if (t < 0 || t >= TT) return;
    int e = (blockIdx.x & 63) * 256 + threadIdx.x;  // 0..16383
    int b = e >> 10, jh = e & 1023;
    float g[4];
    #pragma unroll
    for (int gi = 0; gi < 4; gi++) {
        int r = gi * 1024 + jh;
        float s = 0.f;
        #pragma unroll
        for (int sl = 0; sl < 8; sl++)
            s += gp[((size_t)((cs * 8 + sl) * 16 + b)) * 4096 + r];
        g[gi] = s;
    }
    const float* bi; const float* bh; float* hd;
    if (cs == 0)      { bi = bih0; bh = bhh0; hd = h0r + (size_t)((d + 1) & 3) * 16384; }
    else if (cs == 1) { bi = bih1; bh = bhh1; hd = h1r + (size_t)(d & 3) * 16384; }
    else              { bi = bih2; bh = bhh2; hd = h2 + (size_t)(t + 1) * 16384; }
    #pragma unroll
    for (int gi = 0; gi < 4; gi++) g[gi] += bi[gi * 1024 + jh] + bh[gi * 1024 + jh];
    float ig = 1.f / (1.f + __expf(-g[0]));
    float fg = 1.f / (1.f + __expf(-g[1]));
    float gg = tanhf(g[2]);
    float og = 1.f / (1.f + __expf(-g[3]));
    float* cp = cbuf + (size_t)(cs * 16 + b) * 1024 + jh;
    float c = fg * (*cp) + ig * gg;
    *cp = c;
    hd[(size_t)b * 1024 + jh] = og * tanhf(c);
}

// ---------------------------------------------------------------------------
// C[M, N] (+)= A @ B^T.  A row m: (aIdx? aIdx[m] : m)*lda.  N = gridDim.x*64.
__global__ __launch_bounds__(256) void k_gemm_nt(
    const float* __restrict__ A, int lda, long sA, const int* __restrict__ aIdx,
    const float* __restrict__ Bm, int ldb, long sB,
    float* __restrict__ C, int ldc, long sC,
    int M, int K, int accum)
{
    __shared__ float As[32][64];
    __shared__ float Bs[32][64];
    int z = blockIdx.z;
    const float* Ab = A + (size_t)z * sA;
    const float* Bb = Bm + (size_t)z * sB;
    float* Cb = C + (size_t)z * sC;
    int m0 = blockIdx.y * 64, n0 = blockIdx.x * 64;
    int tid = threadIdx.x;
    int lr = tid >> 2, lk = (tid & 3) * 4;
    int tx = tid & 15, ty = tid >> 4;
    float acc[4][4] = {};
    int arow = m0 + lr;
    bool av = arow < M;
    int rr = av ? (aIdx ? aIdx[arow] : arow) : 0;
    const float* ap = Ab + (size_t)rr * lda;
    const float* bp = Bb + (size_t)(n0 + lr) * ldb;
    for (int k0 = 0; k0 < K; k0 += 32) {
        float4 a0 = make_float4(0.f, 0.f, 0.f, 0.f), a1 = a0;
        if (av) {
            a0 = *(const float4*)(ap + k0 + lk);
            a1 = *(const float4*)(ap + k0 + 16 + lk);
        }
        float4 b0 = *(const float4*)(bp + k0 + lk);
        float4 b1 = *(const float4*)(bp + k0 + 16 + lk);
        __syncthreads();
        As[lk + 0][lr] = a0.x; As[lk + 1][lr] = a0.y; As[lk + 2][lr] = a0.z; As[lk + 3][lr] = a0.w;
        As[16 + lk + 0][lr] = a1.x; As[16 + lk + 1][lr] = a1.y; As[16 + lk + 2][lr] = a1.z; As[16 + lk + 3][lr] = a1.w;
        Bs[lk + 0][lr] = b0.x; Bs[lk + 1][lr] = b0.y; Bs[lk + 2][lr] = b0.z; Bs[lk + 3][lr] = b0.w;
        Bs[16 + lk + 0][lr] = b1.x; Bs[16 + lk + 1][lr] = b1.y; Bs[16 + lk + 2][lr] = b1.z; Bs[16 + lk + 3][lr] = b1.w;
        __syncthreads();
        #pragma unroll
        for (int k = 0; k < 32; k++) {
            float4 a = *(const float4*)&As[k][ty * 4];
            float4 b = *(const float4*)&Bs[k][tx * 4];
            float am[4] = {a.x, a.y, a.z, a.w};
            float bn[4] = {b.x, b.y, b.z, b.w};
            #pragma unroll
            for (int i = 0; i < 4; i++)
                #pragma unroll
                for (int j = 0; j < 4; j++)
                    acc[i][j] = fmaf(am[i], bn[j], acc[i][j]);
        }
    }
    #pragma unroll
    for (int i = 0; i < 4; i++) {
        int row = m0 + ty * 4 + i;
        if (row < M) {
            float* cp = Cb + (size_t)row * ldc + n0 + tx * 4;
            float4 v = make_float4(acc[i][0], acc[i][1], acc[i][2], acc[i][3]);
            if (accum) {
                float4 o = *(const float4*)cp;
                v.x += o.x; v.y += o.y; v.z += o.z; v.w += o.w;
            }
            *(float4*)cp = v;
        }
    }
}

// ---------------------------------------------------------------------------
// C[M, N] = A[M,K] @ B[K,N], batched via blockIdx.z. N multiple of 64.
__global__ __launch_bounds__(256) void k_gemm_nn(
    const float* __restrict__ A, int lda, long sA,
    const float* __restrict__ Bm, int ldb, long sB,
    float* __restrict__ C, int ldc, long sC,
    int M, int K)
{
    __shared__ float As[32][64];
    __shared__ float Bs[32][64];
    int z = blockIdx.z;
    const float* Ab = A + (size_t)z * sA;
    const float* Bb = Bm + (size_t)z * sB;
    float* Cb = C + (size_t)z * sC;
    int m0 = blockIdx.y * 64, n0 = blockIdx.x * 64;
    int tid = threadIdx.x;
    int lr = tid >> 2, lk = (tid & 3) * 4;
    int bkr = tid >> 3, bng = (tid & 7) * 8;
    int tx = tid & 15, ty = tid >> 4;
    float acc[4][4] = {};
    int arow = m0 + lr;
    bool av = arow < M;
    const float* ap = Ab + (size_t)(av ? arow : 0) * lda;
    const float* bp = Bb + (size_t)bkr * ldb + n0 + bng;
    for (int k0 = 0; k0 < K; k0 += 32) {
        float4 a0 = make_float4(0.f, 0.f, 0.f, 0.f), a1 = a0;
        if (av) {
            a0 = *(const float4*)(ap + k0 + lk);
            a1 = *(const float4*)(ap + k0 + 16 + lk);
        }
        float4 b0 = *(const float4*)(bp + (size_t)k0 * ldb);
        float4 b1 = *(const float4*)(bp + (size_t)k0 * ldb + 4);
        __syncthreads();
        As[lk + 0][lr] = a0.x; As[lk + 1][lr] = a0.y; As[lk + 2][lr] = a0.z; As[lk + 3][lr] = a0.w;
        As[16 + lk + 0][lr] = a1.x; As[16 + lk + 1][lr] = a1.y; As[16 + lk + 2][lr] = a1.z; As[16 + lk + 3][lr] = a1.w;
        *(float4*)&Bs[bkr][bng] = b0;
        *(float4*)&Bs[bkr][bng + 4] = b1;
        __syncthreads();
        #pragma unroll
        for (int k = 0; k < 32; k++) {
            float4 a = *(const float4*)&As[k][ty * 4];
            float4 b = *(const float4*)&Bs[k][tx * 4];
            float am[4] = {a.x, a.y, a.z, a.w};
            float bn[4] = {b.x, b.y, b.z, b.w};
            #pragma unroll
            for (int i = 0; i < 4; i++)
                #pragma unroll
                for (int j = 0; j < 4; j++)
                    acc[i][j] = fmaf(am[i], bn[j], acc[i][j]);
        }
    }
    #pragma unroll
    for (int i = 0; i < 4; i++) {
        int row = m0 + ty * 4 + i;
        if (row < M) {
            float* cp = Cb + (size_t)row * ldc + n0 + tx * 4;
            *(float4*)cp = make_float4(acc[i][0], acc[i][1], acc[i][2], acc[i][3]);
        }
    }
}

// ---------------------------------------------------------------------------
__global__ __launch_bounds__(256) void k_softmax(float* __restrict__ sc)
{
    __shared__ float red[4];
    float* p = sc + (size_t)blockIdx.x * 512;
    int tid = threadIdx.x;
    float a = p[tid], b = p[tid + 256];
    float m = fmaxf(a, b);
    for (int o = 32; o; o >>= 1) m = fmaxf(m, __shfl_xor(m, o, 64));
    if ((tid & 63) == 0) red[tid >> 6] = m;
    __syncthreads();
    m = fmaxf(fmaxf(red[0], red[1]), fmaxf(red[2], red[3]));
    __syncthreads();
    float ea = __expf(a - m), eb = __expf(b - m);
    float s = ea + eb;
    for (int o = 32; o; o >>= 1) s += __shfl_xor(s, o, 64);
    if ((tid & 63) == 0) red[tid >> 6] = s;
    __syncthreads();
    s = red[0] + red[1] + red[2] + red[3];
    float inv = 1.f / s;
    p[tid] = ea * inv;
    p[tid + 256] = eb * inv;
}

// ---------------------------------------------------------------------------
__global__ __launch_bounds__(256) void k_tanh_bias(float* __restrict__ hid,
                                                   const float* __restrict__ b1)
{
    size_t i = (size_t)blockIdx.x * 256 + threadIdx.x;
    hid[i] = tanhf(hid[i] + b1[i & 1023]);
}

// ---------------------------------------------------------------------------
__global__ __launch_bounds__(256) void k_loss(const float* __restrict__ logits,
                                              const float* __restrict__ b2,
                                              const int* __restrict__ dec_out_m,
                                              float* __restrict__ out)
{
    __shared__ float red[4];
    int m = blockIdx.x;
    const float* p = logits + (size_t)m * 1024;
    int tid = threadIdx.x;
    float v0 = p[tid] + b2[tid];
    float v1 = p[tid + 256] + b2[tid + 256];
    float v2 = p[tid + 512] + b2[tid + 512];
    float v3 = p[tid + 768] + b2[tid + 768];
    float mx = fmaxf(fmaxf(v0, v1), fmaxf(v2, v3));
    for (int o = 32; o; o >>= 1) mx = fmaxf(mx, __shfl_xor(mx, o, 64));
    if ((tid & 63) == 0) red[tid >> 6] = mx;
    __syncthreads();
    mx = fmaxf(fmaxf(red[0], red[1]), fmaxf(red[2], red[3]));
    __syncthreads();
    float s = __expf(v0 - mx) + __expf(v1 - mx) + __expf(v2 - mx) + __expf(v3 - mx);
    for (int o = 32; o; o >>= 1) s += __shfl_xor(s, o, 64);
    if ((tid & 63) == 0) red[tid >> 6] = s;
    __syncthreads();
    if (tid == 0) {
        float ssum = red[0] + red[1] + red[2] + red[3];
        int tgt = dec_out_m[m];
        float tv = p[tgt] + b2[tgt];
        atomicAdd(out, (mx + logf(ssum) - tv) * (1.0f / 4112.0f));
    }
}

// ---------------------------------------------------------------------------
extern "C" void kernel_launch(void* const* d_in, const int* in_sizes, int n_in,
                              void* d_out, int out_size, void* d_ws, size_t ws_size,
                              hipStream_t stream)
{
    const int*   tokens = (const int*)d_in[0];
    const float* enc    = (const float*)d_in[1];
    const float* emb    = (const float*)d_in[2];
    const float* Wih0   = (const float*)d_in[3];
    const float* Whh0   = (const float*)d_in[4];
    const float* bih0   = (const float*)d_in[5];
    const float* bhh0   = (const float*)d_in[6];
    const float* Wih1   = (const float*)d_in[7];
    const float* Whh1   = (const float*)d_in[8];
    const float* bih1   = (const float*)d_in[9];
    const float* bhh1   = (const float*)d_in[10];
    const float* Wih2   = (const float*)d_in[11];
    const float* Whh2   = (const float*)d_in[12];
    const float* bih2   = (const float*)d_in[13];
    const float* bhh2   = (const float*)d_in[14];
    const float* W1     = (const float*)d_in[15];
    const float* b1     = (const float*)d_in[16];
    const float* W2     = (const float*)d_in[17];
    const float* b2     = (const float*)d_in[18];

    float* ws  = (float*)d_ws;
    float* out = (float*)d_out;

    if (ws_size < TOTAL_FLOATS * sizeof(float)) {   // diagnostic sentinel
        k_fail<<<1, 1, 0, stream>>>(out);
        return;
    }

    float* h2   = ws + OFF_H2;
    float* h0r  = ws + OFF_H0R;
    float* h1r  = ws + OFF_H1R;
    float* cbuf = ws + OFF_C;
    float* gp   = ws + OFF_GP;
    float* sc   = ws + OFF_SC;
    float* ctx  = ws + OFF_CTX;
    float* hid  = ws + OFF_HID;
    float* lg   = ws + OFF_LOG;
    int* dec_in  = (int*)(ws + OFF_INT);
    int* dec_out = dec_in + 4112;
    int* hsrow   = dec_in + 8224;

    k_init<<<192, 256, 0, stream>>>(tokens, ws, out);

    // sequential recurrence: wavefront diagonals d = t + layer
    for (int d = 0; d < 259; d++) {
        k_rec_gates<<<384, 256, 0, stream>>>(emb, Wih0, Whh0, Wih1, Whh1,
                                             Wih2, Whh2, h0r, h1r, h2, dec_in, gp, d);
        k_rec_up<<<192, 256, 0, stream>>>(gp, bih0, bhh0, bih1, bhh1,
                                          bih2, bhh2, h0r, h1r, h2, cbuf, d);
    }

    // scores[b][t][s] = hs[b,t] . enc[b,s]   (batched NT, A = h2 slots 1..257)
    k_gemm_nt<<<dim3(8, 5, 16), 256, 0, stream>>>(h2 + 16384, 16384, 1024, nullptr,
                                                  enc, 1024, (long)512 * 1024,
                                                  sc, 512, (long)257 * 512, TT, 1024, 0);
    k_softmax<<<4112, 256, 0, stream>>>(sc);
    // ctx[b][t][h] = attn @ enc   (batched NN)
    k_gemm_nn<<<dim3(16, 5, 16), 256, 0, stream>>>(sc, 512, (long)257 * 512,
                                                   enc, 1024, (long)512 * 1024,
                                                   ctx, 1024, (long)257 * 1024, TT, 512);
    // hidden = hs @ W1[:, :1024]^T + ctx @ W1[:, 1024:]^T, then tanh(+b1)
    k_gemm_nt<<<dim3(16, 65, 1), 256, 0, stream>>>(h2, 1024, 0, hsrow,
                                                   W1, 2048, 0,
                                                   hid, 1024, 0, BT, 1024, 0);
    k_gemm_nt<<<dim3(16, 65, 1), 256, 0, stream>>>(ctx, 1024, 0, nullptr,
                                                   W1 + 1024, 2048, 0,
                                                   hid, 1024, 0, BT, 1024, 1);
    k_tanh_bias<<<16448, 256, 0, stream>>>(hid, b1);
    // logits = hidden @ W2^T ; loss = mean(lse - logit[target])
    k_gemm_nt<<<dim3(16, 65, 1), 256, 0, stream>>>(hid, 1024, 0, nullptr,
                                                   W2, 1024, 0,
                                                   lg, 1024, 0, BT, 1024, 0);
    k_loss<<<4112, 256, 0, stream>>>(lg, b2, dec_out, out);
}

// Round 3
// 5423.105 us; speedup vs baseline: 2.4606x; 2.4606x over previous
//
#include <hip/hip_runtime.h>
#include <math.h>

// ---------------------------------------------------------------------------
// Decoder: 3-layer LSTM + dot attention + MLP + CE loss.  B=16, T=257, H=1024.
// Round 3: bf16 MFMA recurrence, one fused kernel per diagonal.
//   - weights hh0/ih1/hh1/ih2/hh2 converted to bf16 once (k_cvt5)
//   - k_rec_step: WG=512thr=8 waves = 4 gates x 2 K-halves; MFMA 16x16x32
//     (A = h [b][k] bf16, B = W rows [n][k] bf16, both direct 16B/lane loads),
//     LDS reduce, nonlinearity, h/c update. cell0 reads emb/Wih0 fp32 directly.
//   - epilogue: bf16-A / fp32-B / bf16-C scalar GEMMs (unchanged structure).
// Workspace: 72 MB (known-safe budget).
// ---------------------------------------------------------------------------

namespace {
constexpr int TT = 257;
constexpr int BT = 4112;

// ushort (bf16) element offsets
constexpr size_t OFF_WB  = 0;                   // 5 x [4096][1024] bf16
constexpr size_t SZ_W1   = 4194304;
constexpr size_t OFF_H2B = 20971520;            // [258][16][1024]
constexpr size_t OFF_H0R = 25198592;            // [4][16][1024] ring
constexpr size_t OFF_H1R = 25264128;            // [4][16][1024] ring
constexpr size_t OFF_SC  = 25329664;            // [16][257][512]
constexpr size_t OFF_CTX = 27435008;            // [4112][1024]
constexpr size_t OFF_HID = 31645696;            // [4112][1024]
constexpr size_t OFF_LG  = OFF_SC;              // alias over sc+ctx (dead)
constexpr size_t END_BF  = 35856384;            // ushort elems
constexpr size_t OFF_CB_BYTES  = END_BF * 2;            // cbuf fp32 [3][16][1024]
constexpr size_t OFF_INT_BYTES = OFF_CB_BYTES + 196608; // 3 x 4112 ints
constexpr size_t TOTAL_BYTES   = OFF_INT_BYTES + 49344; // 71,958,720
}

typedef __attribute__((ext_vector_type(8))) short bf16x8;
typedef __attribute__((ext_vector_type(4))) float f32x4;

__device__ __forceinline__ float bf2f(ushort u) {
    union { unsigned int v; float f; } x; x.v = ((unsigned int)u) << 16; return x.f;
}
__device__ __forceinline__ ushort f2bf(float f) {
    union { float f; unsigned int v; } x; x.f = f;
    return (ushort)((x.v + 0x7fff + ((x.v >> 16) & 1)) >> 16);
}
__device__ __forceinline__ float sigm(float x) { return 1.f / (1.f + __expf(-x)); }

// ---------------------------------------------------------------------------
__global__ void k_fail(float* out) { out[0] = -123456.0f; }

// ---------------------------------------------------------------------------
__global__ __launch_bounds__(256) void k_init(const int* __restrict__ tokens,
                                              ushort* __restrict__ wsb,
                                              float* __restrict__ out)
{
    int i = blockIdx.x * 256 + threadIdx.x;          // 65536 threads
    float* cbuf  = (float*)((char*)wsb + OFF_CB_BYTES);
    int* dec_in  = (int*)((char*)wsb + OFF_INT_BYTES);
    int* dec_out = dec_in + 4112;
    int* hsrow   = dec_in + 8224;
    if (i < 4112) {
        int t = i >> 4, b = i & 15;                  // t-major
        dec_in[i] = (t == 0) ? 1 : tokens[b * 256 + (t - 1)];
        int bb = i / 257, tt = i % 257;              // m-order (b-major)
        dec_out[i] = (tt < 256) ? tokens[bb * 256 + tt] : 2;
        hsrow[i] = (tt + 1) * 16 + bb;
    }
    if (i < 65536) { wsb[OFF_H0R + i] = 0; wsb[OFF_H1R + i] = 0; }
    if (i < 16384) wsb[OFF_H2B + i] = 0;             // h2 slot 0
    if (i < 49152) cbuf[i] = 0.f;
    if (i == 0) out[0] = 0.f;
}

// ---------------------------------------------------------------------------
// convert 5 fp32 [4096][1024] matrices to bf16. grid (2048, 5), 8 elems/thread
__global__ __launch_bounds__(256) void k_cvt5(
    const float* __restrict__ s0, const float* __restrict__ s1,
    const float* __restrict__ s2, const float* __restrict__ s3,
    const float* __restrict__ s4, ushort* __restrict__ wb)
{
    int m = blockIdx.y;
    const float* src = (m == 0) ? s0 : (m == 1) ? s1 : (m == 2) ? s2 : (m == 3) ? s3 : s4;
    size_t idx = ((size_t)blockIdx.x * 256 + threadIdx.x) * 8;
    float4 a = *(const float4*)(src + idx);
    float4 b = *(const float4*)(src + idx + 4);
    uint4 o;
    o.x = (unsigned)f2bf(a.x) | ((unsigned)f2bf(a.y) << 16);
    o.y = (unsigned)f2bf(a.z) | ((unsigned)f2bf(a.w) << 16);
    o.z = (unsigned)f2bf(b.x) | ((unsigned)f2bf(b.y) << 16);
    o.w = (unsigned)f2bf(b.z) | ((unsigned)f2bf(b.w) << 16);
    *(uint4*)(wb + (size_t)m * SZ_W1 + idx) = o;
}

// ---------------------------------------------------------------------------
// Fused recurrence step for diagonal d. 192 WGs x 512 threads.
// WG -> (cell = bx>>6, ublk = bx&63): 16 hidden units, all 4 gates, full K.
// wave w: gate g = w&3, K-half kh = w>>2. MFMA 16x16x32 bf16.
__global__ __launch_bounds__(512) void k_rec_step(
    const ushort* __restrict__ wb,
    const float* __restrict__ emb, const float* __restrict__ Wih0,
    const float* __restrict__ bih0, const float* __restrict__ bhh0,
    const float* __restrict__ bih1, const float* __restrict__ bhh1,
    const float* __restrict__ bih2, const float* __restrict__ bhh2,
    ushort* __restrict__ h0r, ushort* __restrict__ h1r,
    ushort* __restrict__ h2b, float* __restrict__ cbuf,
    const int* __restrict__ dec_in, int d)
{
    __shared__ float lds[2][4][16][16];
    int cell = blockIdx.x >> 6, ublk = blockIdx.x & 63;
    int t = d - cell;
    if (t < 0 || t >= TT) return;
    int tid = threadIdx.x;
    int w = tid >> 6, g = w & 3, kh = w >> 2;
    int l15 = tid & 15, quad = (tid & 63) >> 4;
    int n = g * 1024 + ublk * 16 + l15;              // gate row

    f32x4 acc = {0.f, 0.f, 0.f, 0.f};

    if (cell == 0 && kh == 0) {
        // x-part: emb[dec_in[t]] @ Wih0[:, :512]^T  (fp32 sources, cvt in reg)
        int tok = dec_in[d * 16 + l15];
        const float* ap = emb + (size_t)tok * 512 + quad * 8;
        const float* wp = Wih0 + (size_t)n * 1536 + quad * 8;
        for (int k0 = 0; k0 < 512; k0 += 32) {
            float4 a0 = *(const float4*)(ap + k0);
            float4 a1 = *(const float4*)(ap + k0 + 4);
            float4 w0 = *(const float4*)(wp + k0);
            float4 w1 = *(const float4*)(wp + k0 + 4);
            bf16x8 af, wf;
            af[0] = (short)f2bf(a0.x); af[1] = (short)f2bf(a0.y);
            af[2] = (short)f2bf(a0.z); af[3] = (short)f2bf(a0.w);
            af[4] = (short)f2bf(a1.x); af[5] = (short)f2bf(a1.y);
            af[6] = (short)f2bf(a1.z); af[7] = (short)f2bf(a1.w);
            wf[0] = (short)f2bf(w0.x); wf[1] = (short)f2bf(w0.y);
            wf[2] = (short)f2bf(w0.z); wf[3] = (short)f2bf(w0.w);
            wf[4] = (short)f2bf(w1.x); wf[5] = (short)f2bf(w1.y);
            wf[6] = (short)f2bf(w1.z); wf[7] = (short)f2bf(w1.w);
            acc = __builtin_amdgcn_mfma_f32_16x16x32_bf16(af, wf, acc, 0, 0, 0);
        }
    } else {
        const ushort* Ab; const ushort* Wb;
        if (cell == 0)      { Ab = h0r + ((d - 1) & 3) * 16384; Wb = wb + 0 * SZ_W1; }
        else if (cell == 1) {
            if (kh == 0)    { Ab = h0r + ((d - 1) & 3) * 16384; Wb = wb + 1 * SZ_W1; }
            else            { Ab = h1r + ((d - 2) & 3) * 16384; Wb = wb + 2 * SZ_W1; }
        } else {
            if (kh == 0)    { Ab = h1r + ((d - 2) & 3) * 16384; Wb = wb + 3 * SZ_W1; }
            else            { Ab = h2b + (size_t)(d - 2) * 16384; Wb = wb + 4 * SZ_W1; }
        }
        const ushort* ap = Ab + l15 * 1024 + quad * 8;
        const ushort* wp = Wb + (size_t)n * 1024 + quad * 8;
        #pragma unroll 8
        for (int k0 = 0; k0 < 1024; k0 += 32) {
            bf16x8 af = *(const bf16x8*)(ap + k0);
            bf16x8 wf = *(const bf16x8*)(wp + k0);
            acc = __builtin_amdgcn_mfma_f32_16x16x32_bf16(af, wf, acc, 0, 0, 0);
        }
    }

    // C/D layout: col = lane&15 (= n/unit), row = quad*4+reg (= batch)
    #pragma unroll
    for (int r = 0; r < 4; r++) lds[kh][g][quad * 4 + r][l15] = acc[r];
    __syncthreads();

    if (tid < 256) {
        int b = tid >> 4, j16 = tid & 15;
        int j = ublk * 16 + j16;
        const float* bi; const float* bh; ushort* hdst;
        if (cell == 0)      { bi = bih0; bh = bhh0; hdst = h0r + (d & 3) * 16384; }
        else if (cell == 1) { bi = bih1; bh = bhh1; hdst = h1r + ((d - 1) & 3) * 16384; }
        else                { bi = bih2; bh = bhh2; hdst = h2b + (size_t)(d - 1) * 16384; }
        float gv[4];
        #pragma unroll
        for (int gi = 0; gi < 4; gi++)
            gv[gi] = lds[0][gi][b][j16] + lds[1][gi][b][j16]
                   + bi[gi * 1024 + j] + bh[gi * 1024 + j];
        float ig = sigm(gv[0]), fg = sigm(gv[1]);
        float gg = tanhf(gv[2]), og = sigm(gv[3]);
        float* cp = cbuf + (size_t)(cell * 16 + b) * 1024 + j;
        float c = fg * (*cp) + ig * gg;
        *cp = c;
        hdst[b * 1024 + j] = f2bf(og * tanhf(c));
    }
}

// ---------------------------------------------------------------------------
// C[M,N] (+)= A(bf16) @ B(fp32)^T -> C bf16. A row gather via aIdx; batch z.
__global__ __launch_bounds__(256) void k_gemm_nt_b(
    const ushort* __restrict__ A, int lda, long sA, const int* __restrict__ aIdx,
    const float* __restrict__ Bm, int ldb, long sB,
    ushort* __restrict__ C, int ldc, long sC,
    int M, int K, int accum)
{
    __shared__ float As[32][64];
    __shared__ float Bs[32][64];
    int z = blockIdx.z;
    const ushort* Ab = A + (size_t)z * sA;
    const float* Bb = Bm + (size_t)z * sB;
    ushort* Cb = C + (size_t)z * sC;
    int m0 = blockIdx.y * 64, n0 = blockIdx.x * 64;
    int tid = threadIdx.x;
    int lr = tid >> 2, lq = (tid & 3) * 8, lk = (tid & 3) * 4;
    int tx = tid & 15, ty = tid >> 4;
    float acc[4][4] = {};
    int arow = m0 + lr;
    bool av = arow < M;
    int rr = av ? (aIdx ? aIdx[arow] : arow) : 0;
    const ushort* ap = Ab + (size_t)rr * lda;
    const float* bp = Bb + (size_t)(n0 + lr) * ldb;
    for (int k0 = 0; k0 < K; k0 += 32) {
        uint4 araw = make_uint4(0, 0, 0, 0);
        if (av) araw = *(const uint4*)(ap + k0 + lq);
        float4 b0 = *(const float4*)(bp + k0 + lk);
        float4 b1 = *(const float4*)(bp + k0 + 16 + lk);
        __syncthreads();
        const ushort* ar = (const ushort*)&araw;
        #pragma unroll
        for (int i = 0; i < 8; i++) As[lq + i][lr] = bf2f(ar[i]);
        Bs[lk + 0][lr] = b0.x; Bs[lk + 1][lr] = b0.y; Bs[lk + 2][lr] = b0.z; Bs[lk + 3][lr] = b0.w;
        Bs[16 + lk + 0][lr] = b1.x; Bs[16 + lk + 1][lr] = b1.y; Bs[16 + lk + 2][lr] = b1.z; Bs[16 + lk + 3][lr] = b1.w;
        __syncthreads();
        #pragma unroll
        for (int k = 0; k < 32; k++) {
            float4 a = *(const float4*)&As[k][ty * 4];
            float4 b = *(const float4*)&Bs[k][tx * 4];
            float am[4] = {a.x, a.y, a.z, a.w};
            float bn[4] = {b.x, b.y, b.z, b.w};
            #pragma unroll
            for (int i = 0; i < 4; i++)
                #pragma unroll
                for (int j = 0; j < 4; j++)
                    acc[i][j] = fmaf(am[i], bn[j], acc[i][j]);
        }
    }
    #pragma unroll
    for (int i = 0; i < 4; i++) {
        int row = m0 + ty * 4 + i;
        if (row < M) {
            ushort* cp = Cb + (size_t)row * ldc + n0 + tx * 4;
            float v[4] = {acc[i][0], acc[i][1], acc[i][2], acc[i][3]};
            if (accum) {
                ushort4 o = *(const ushort4*)cp;
                v[0] += bf2f(o.x); v[1] += bf2f(o.y); v[2] += bf2f(o.z); v[3] += bf2f(o.w);
            }
            ushort4 s;
            s.x = f2bf(v[0]); s.y = f2bf(v[1]); s.z = f2bf(v[2]); s.w = f2bf(v[3]);
            *(ushort4*)cp = s;
        }
    }
}

// ---------------------------------------------------------------------------
// C[M,N] = A(bf16)[M,K] @ B(fp32)[K,N] -> C bf16, batched via z.
__global__ __launch_bounds__(256) void k_gemm_nn_b(
    const ushort* __restrict__ A, int lda, long sA,
    const float* __restrict__ Bm, int ldb, long sB,
    ushort* __restrict__ C, int ldc, long sC,
    int M, int K)
{
    __shared__ float As[32][64];
    __shared__ float Bs[32][64];
    int z = blockIdx.z;
    const ushort* Ab = A + (size_t)z * sA;
    const float* Bb = Bm + (size_t)z * sB;
    ushort* Cb = C + (size_t)z * sC;
    int m0 = blockIdx.y * 64, n0 = blockIdx.x * 64;
    int tid = threadIdx.x;
    int lr = tid >> 2, lq = (tid & 3) * 8;
    int bkr = tid >> 3, bng = (tid & 7) * 8;
    int tx = tid & 15, ty = tid >> 4;
    float acc[4][4] = {};
    int arow = m0 + lr;
    bool av = arow < M;
    const ushort* ap = Ab + (size_t)(av ? arow : 0) * lda;
    const float* bp = Bb + (size_t)bkr * ldb + n0 + bng;
    for (int k0 = 0; k0 < K; k0 += 32) {
        uint4 araw = make_uint4(0, 0, 0, 0);
        if (av) araw = *(const uint4*)(ap + k0 + lq);
        float4 b0 = *(const float4*)(bp + (size_t)k0 * ldb);
        float4 b1 = *(const float4*)(bp + (size_t)k0 * ldb + 4);
        __syncthreads();
        const ushort* ar = (const ushort*)&araw;
        #pragma unroll
        for (int i = 0; i < 8; i++) As[lq + i][lr] = bf2f(ar[i]);
        *(float4*)&Bs[bkr][bng] = b0;
        *(float4*)&Bs[bkr][bng + 4] = b1;
        __syncthreads();
        #pragma unroll
        for (int k = 0; k < 32; k++) {
            float4 a = *(const float4*)&As[k][ty * 4];
            float4 b = *(const float4*)&Bs[k][tx * 4];
            float am[4] = {a.x, a.y, a.z, a.w};
            float bn[4] = {b.x, b.y, b.z, b.w};
            #pragma unroll
            for (int i = 0; i < 4; i++)
                #pragma unroll
                for (int j = 0; j < 4; j++)
                    acc[i][j] = fmaf(am[i], bn[j], acc[i][j]);
        }
    }
    #pragma unroll
    for (int i = 0; i < 4; i++) {
        int row = m0 + ty * 4 + i;
        if (row < M) {
            ushort* cp = Cb + (size_t)row * ldc + n0 + tx * 4;
            ushort4 s;
            s.x = f2bf(acc[i][0]); s.y = f2bf(acc[i][1]);
            s.z = f2bf(acc[i][2]); s.w = f2bf(acc[i][3]);
            *(ushort4*)cp = s;
        }
    }
}

// ---------------------------------------------------------------------------
__global__ __launch_bounds__(256) void k_softmax_b(ushort* __restrict__ sc)
{
    __shared__ float red[4];
    ushort* p = sc + (size_t)blockIdx.x * 512;
    int tid = threadIdx.x;
    float a = bf2f(p[tid]), b = bf2f(p[tid + 256]);
    float m = fmaxf(a, b);
    for (int o = 32; o; o >>= 1) m = fmaxf(m, __shfl_xor(m, o, 64));
    if ((tid & 63) == 0) red[tid >> 6] = m;
    __syncthreads();
    m = fmaxf(fmaxf(red[0], red[1]), fmaxf(red[2], red[3]));
    __syncthreads();
    float ea = __expf(a - m), eb = __expf(b - m);
    float s = ea + eb;
    for (int o = 32; o; o >>= 1) s += __shfl_xor(s, o, 64);
    if ((tid & 63) == 0) red[tid >> 6] = s;
    __syncthreads();
    s = red[0] + red[1] + red[2] + red[3];
    float inv = 1.f / s;
    p[tid] = f2bf(ea * inv);
    p[tid + 256] = f2bf(eb * inv);
}

// ---------------------------------------------------------------------------
__global__ __launch_bounds__(256) void k_tanh_bias_b(ushort* __restrict__ hid,
                                                     const float* __restrict__ b1)
{
    size_t i = (size_t)blockIdx.x * 256 + threadIdx.x;
    hid[i] = f2bf(tanhf(bf2f(hid[i]) + b1[i & 1023]));
}

// ---------------------------------------------------------------------------
__global__ __launch_bounds__(256) void k_loss_b(const ushort* __restrict__ logits,
                                                const float* __restrict__ b2,
                                                const int* __restrict__ dec_out_m,
                                                float* __restrict__ out)
{
    __shared__ float red[4];
    int m = blockIdx.x;
    const ushort* p = logits + (size_t)m * 1024;
    int tid = threadIdx.x;
    float v0 = bf2f(p[tid]) + b2[tid];
    float v1 = bf2f(p[tid + 256]) + b2[tid + 256];
    float v2 = bf2f(p[tid + 512]) + b2[tid + 512];
    float v3 = bf2f(p[tid + 768]) + b2[tid + 768];
    float mx = fmaxf(fmaxf(v0, v1), fmaxf(v2, v3));
    for (int o = 32; o; o >>= 1) mx = fmaxf(mx, __shfl_xor(mx, o, 64));
    if ((tid & 63) == 0) red[tid >> 6] = mx;
    __syncthreads();
    mx = fmaxf(fmaxf(red[0], red[1]), fmaxf(red[2], red[3]));
    __syncthreads();
    float s = __expf(v0 - mx) + __expf(v1 - mx) + __expf(v2 - mx) + __expf(v3 - mx);
    for (int o = 32; o; o >>= 1) s += __shfl_xor(s, o, 64);
    if ((tid & 63) == 0) red[tid >> 6] = s;
    __syncthreads();
    if (tid == 0) {
        float ssum = red[0] + red[1] + red[2] + red[3];
        int tgt = dec_out_m[m];
        float tv = bf2f(p[tgt]) + b2[tgt];
        atomicAdd(out, (mx + logf(ssum) - tv) * (1.0f / 4112.0f));
    }
}

// ---------------------------------------------------------------------------
extern "C" void kernel_launch(void* const* d_in, const int* in_sizes, int n_in,
                              void* d_out, int out_size, void* d_ws, size_t ws_size,
                              hipStream_t stream)
{
    const int*   tokens = (const int*)d_in[0];
    const float* enc    = (const float*)d_in[1];
    const float* emb    = (const float*)d_in[2];
    const float* Wih0   = (const float*)d_in[3];
    const float* Whh0   = (const float*)d_in[4];
    const float* bih0   = (const float*)d_in[5];
    const float* bhh0   = (const float*)d_in[6];
    const float* Wih1   = (const float*)d_in[7];
    const float* Whh1   = (const float*)d_in[8];
    const float* bih1   = (const float*)d_in[9];
    const float* bhh1   = (const float*)d_in[10];
    const float* Wih2   = (const float*)d_in[11];
    const float* Whh2   = (const float*)d_in[12];
    const float* bih2   = (const float*)d_in[13];
    const float* bhh2   = (const float*)d_in[14];
    const float* W1     = (const float*)d_in[15];
    const float* b1     = (const float*)d_in[16];
    const float* W2     = (const float*)d_in[17];
    const float* b2     = (const float*)d_in[18];

    float* out = (float*)d_out;
    if (ws_size < TOTAL_BYTES) { k_fail<<<1, 1, 0, stream>>>(out); return; }

    ushort* wsb = (ushort*)d_ws;
    ushort* wb  = wsb + OFF_WB;
    ushort* h2b = wsb + OFF_H2B;
    ushort* h0r = wsb + OFF_H0R;
    ushort* h1r = wsb + OFF_H1R;
    ushort* sc  = wsb + OFF_SC;
    ushort* ctx = wsb + OFF_CTX;
    ushort* hid = wsb + OFF_HID;
    ushort* lg  = wsb + OFF_LG;
    float*  cbuf = (float*)((char*)d_ws + OFF_CB_BYTES);
    int* dec_in  = (int*)((char*)d_ws + OFF_INT_BYTES);
    int* dec_out = dec_in + 4112;
    int* hsrow   = dec_in + 8224;

    k_init<<<256, 256, 0, stream>>>(tokens, wsb, out);
    k_cvt5<<<dim3(2048, 5), 256, 0, stream>>>(Whh0, Wih1, Whh1, Wih2, Whh2, wb);

    for (int d = 0; d < 259; d++) {
        k_rec_step<<<192, 512, 0, stream>>>(wb, emb, Wih0,
                                            bih0, bhh0, bih1, bhh1, bih2, bhh2,
                                            h0r, h1r, h2b, cbuf, dec_in, d);
    }

    // scores[b][t][s] = h2(t) . enc[b,s]
    k_gemm_nt_b<<<dim3(8, 5, 16), 256, 0, stream>>>(h2b + 16384, 16384, 1024, nullptr,
                                                    enc, 1024, (long)512 * 1024,
                                                    sc, 512, (long)257 * 512, TT, 1024, 0);
    k_softmax_b<<<4112, 256, 0, stream>>>(sc);
    // ctx = attn @ enc
    k_gemm_nn_b<<<dim3(16, 5, 16), 256, 0, stream>>>(sc, 512, (long)257 * 512,
                                                     enc, 1024, (long)512 * 1024,
                                                     ctx, 1024, (long)257 * 1024, TT, 512);
    // hidden = hs @ W1[:, :1024]^T + ctx @ W1[:, 1024:]^T, then tanh(+b1)
    k_gemm_nt_b<<<dim3(16, 65, 1), 256, 0, stream>>>(h2b, 1024, 0, hsrow,
                                                     W1, 2048, 0,
                                                     hid, 1024, 0, BT, 1024, 0);
    k_gemm_nt_b<<<dim3(16, 65, 1), 256, 0, stream>>>(ctx, 1024, 0, nullptr,
                                                     W1 + 1024, 2048, 0,
                                                     hid, 1024, 0, BT, 1024, 1);
    k_tanh_bias_b<<<16448, 256, 0, stream>>>(hid, b1);
    // logits = hidden @ W2^T ; loss
    k_gemm_nt_b<<<dim3(16, 65, 1), 256, 0, stream>>>(hid, 1024, 0, nullptr,
                                                     W2, 1024, 0,
                                                     lg, 1024, 0, BT, 1024, 0);
    k_loss_b<<<4112, 256, 0, stream>>>(lg, b2, dec_out, out);
}

// Round 4
// 5154.202 us; speedup vs baseline: 2.5890x; 1.0522x over previous
//
#include <hip/hip_runtime.h>
#include <math.h>

// ---------------------------------------------------------------------------
// Decoder: 3-layer LSTM + dot attention + MLP + CE loss.  B=16, T=257, H=1024.
// Round 4:
//   - recurrence: 1024-thr fused diagonal kernel (16 waves = 4 gates x 4 kh),
//     all-bf16 MFMA including cell0 x-part (wx = Wih0[:, :512] bf16, embB).
//   - epilogue: bf16 MFMA NT-GEMM (64x64 tile, direct fragment loads) for
//     scores/ctx/MLP/logits; enc->encB+encT, W1/W2->bf16, aliased over the
//     recurrence weight region (dead after recurrence).
// Workspace: 76.15 MB (known-safe >= 76.63 MB from round 2).
// ---------------------------------------------------------------------------

namespace {
constexpr int TT = 257;
constexpr int BT = 4112;

// ushort (bf16) element offsets
constexpr size_t SZ_W1   = 4194304;             // one [4096][1024] bf16 matrix
constexpr size_t OFF_WB  = 0;                   // 5 x SZ_W1 (recurrence only)
constexpr size_t OFF_H2B = 20971520;            // [258][16][1024]
constexpr size_t OFF_H0R = 25198592;            // [4][16][1024] ring
constexpr size_t OFF_H1R = 25264128;            // [4][16][1024] ring
constexpr size_t OFF_SC  = 25329664;            // [16][257][512]; embB alias
constexpr size_t OFF_CTX = 27435008;            // [16][257][1024]
constexpr size_t OFF_HID = 31645696;            // [4112][1024]
constexpr size_t OFF_LG  = OFF_SC;              // alias over sc (dead at logits)
constexpr size_t OFF_WX  = 35856384;            // [4096][512] bf16 Wih0 x-part
constexpr size_t END_BF  = 37953536;
// epilogue aliases over the OFF_WB region (weights dead after recurrence):
constexpr size_t OFF_ENCB = 0;                  // [16][512][1024]
constexpr size_t OFF_ENCT = 8388608;            // [16][1024][512]
constexpr size_t OFF_W1B  = 16777216;           // [1024][2048]
constexpr size_t OFF_W2B  = 18874368;           // [1024][1024]  (end 19,922,944)
// embB alias in sc region:
constexpr size_t OFF_EMBB = OFF_SC;             // [1024][512]
constexpr size_t OFF_CB_BYTES  = END_BF * 2;            // cbuf fp32 [3][16][1024]
constexpr size_t OFF_INT_BYTES = OFF_CB_BYTES + 196608; // 3 x 4112 ints
constexpr size_t TOTAL_BYTES   = OFF_INT_BYTES + 49344; // 76,153,024
}

typedef __attribute__((ext_vector_type(8))) short bf16x8;
typedef __attribute__((ext_vector_type(4))) float f32x4;

__device__ __forceinline__ float bf2f(ushort u) {
    union { unsigned int v; float f; } x; x.v = ((unsigned int)u) << 16; return x.f;
}
__device__ __forceinline__ ushort f2bf(float f) {
    union { float f; unsigned int v; } x; x.f = f;
    return (ushort)((x.v + 0x7fff + ((x.v >> 16) & 1)) >> 16);
}
__device__ __forceinline__ float sigm(float x) { return 1.f / (1.f + __expf(-x)); }

// ---------------------------------------------------------------------------
__global__ void k_fail(float* out) { out[0] = -123456.0f; }

// ---------------------------------------------------------------------------
__global__ __launch_bounds__(256) void k_init(const int* __restrict__ tokens,
                                              ushort* __restrict__ wsb,
                                              float* __restrict__ out)
{
    int i = blockIdx.x * 256 + threadIdx.x;          // 65536 threads
    float* cbuf  = (float*)((char*)wsb + OFF_CB_BYTES);
    int* dec_in  = (int*)((char*)wsb + OFF_INT_BYTES);
    int* dec_out = dec_in + 4112;
    int* hsrow   = dec_in + 8224;
    if (i < 4112) {
        int t = i >> 4, b = i & 15;                  // t-major
        dec_in[i] = (t == 0) ? 1 : tokens[b * 256 + (t - 1)];
        int bb = i / 257, tt = i % 257;              // m-order (b-major)
        dec_out[i] = (tt < 256) ? tokens[bb * 256 + tt] : 2;
        hsrow[i] = (tt + 1) * 16 + bb;
    }
    if (i < 65536) { wsb[OFF_H0R + i] = 0; wsb[OFF_H1R + i] = 0; }
    if (i < 16384) wsb[OFF_H2B + i] = 0;             // h2 slot 0
    if (i < 49152) cbuf[i] = 0.f;
    if (i == 0) out[0] = 0.f;
}

// ---------------------------------------------------------------------------
// Pre-recurrence conversions. grid (2048, 7).
// z<5: Whh0/Wih1/Whh1/Wih2/Whh2 -> wb (4M elems each). z=5: Wih0[:, :512]
// strided -> wx (2M). z=6: emb -> embB (512K).
__global__ __launch_bounds__(256) void k_cvt_pre(
    const float* __restrict__ s0, const float* __restrict__ s1,
    const float* __restrict__ s2, const float* __restrict__ s3,
    const float* __restrict__ s4, const float* __restrict__ Wih0,
    const float* __restrict__ emb, ushort* __restrict__ wsb)
{
    int z = blockIdx.y;
    int nblk = (z < 5) ? 2048 : (z == 5 ? 1024 : 256);
    if ((int)blockIdx.x >= nblk) return;
    size_t e = ((size_t)blockIdx.x * 256 + threadIdx.x) * 8;
    const float* src; ushort* dst;
    if (z < 5) {
        src = (z == 0) ? s0 : (z == 1) ? s1 : (z == 2) ? s2 : (z == 3) ? s3 : s4;
        src += e;
        dst = wsb + (size_t)z * SZ_W1 + e;
    } else if (z == 5) {
        size_t row = e >> 9, col = e & 511;
        src = Wih0 + row * 1536 + col;
        dst = wsb + OFF_WX + e;
    } else {
        src = emb + e;
        dst = wsb + OFF_EMBB + e;
    }
    float4 a = *(const float4*)src;
    float4 b = *(const float4*)(src + 4);
    uint4 o;
    o.x = (unsigned)f2bf(a.x) | ((unsigned)f2bf(a.y) << 16);
    o.y = (unsigned)f2bf(a.z) | ((unsigned)f2bf(a.w) << 16);
    o.z = (unsigned)f2bf(b.x) | ((unsigned)f2bf(b.y) << 16);
    o.w = (unsigned)f2bf(b.z) | ((unsigned)f2bf(b.w) << 16);
    *(uint4*)dst = o;
}

// ---------------------------------------------------------------------------
// generic contiguous fp32 -> bf16 (n = grid.x * 2048 elems)
__global__ __launch_bounds__(256) void k_cvt_flat(const float* __restrict__ src,
                                                  ushort* __restrict__ dst)
{
    size_t e = ((size_t)blockIdx.x * 256 + threadIdx.x) * 8;
    float4 a = *(const float4*)(src + e);
    float4 b = *(const float4*)(src + e + 4);
    uint4 o;
    o.x = (unsigned)f2bf(a.x) | ((unsigned)f2bf(a.y) << 16);
    o.y = (unsigned)f2bf(a.z) | ((unsigned)f2bf(a.w) << 16);
    o.z = (unsigned)f2bf(b.x) | ((unsigned)f2bf(b.y) << 16);
    o.w = (unsigned)f2bf(b.z) | ((unsigned)f2bf(b.w) << 16);
    *(uint4*)(dst + e) = o;
}

// ---------------------------------------------------------------------------
// encT[b][h][s] = bf16(enc[b][s][h]).  grid (16, 32, 16), block 256.
__global__ __launch_bounds__(256) void k_enc_t(const float* __restrict__ enc,
                                               ushort* __restrict__ encT)
{
    __shared__ float tile[32][33];
    int b = blockIdx.z, s0 = blockIdx.x * 32, h0 = blockIdx.y * 32;
    int tx = threadIdx.x & 31, ty = threadIdx.x >> 5;   // ty 0..7
    const float* src = enc + (size_t)b * 524288;
    #pragma unroll
    for (int i = 0; i < 4; i++) {
        int s = s0 + ty + i * 8;
        tile[ty + i * 8][tx] = src[(size_t)s * 1024 + h0 + tx];
    }
    __syncthreads();
    ushort* dst = encT + (size_t)b * 524288;
    #pragma unroll
    for (int i = 0; i < 4; i++) {
        int h = h0 + ty + i * 8;
        dst[(size_t)h * 512 + s0 + tx] = f2bf(tile[tx][ty + i * 8]);
    }
}

// ---------------------------------------------------------------------------
// Fused recurrence step for diagonal d. 192 WGs x 1024 threads (16 waves).
// WG -> (cell = bx>>6, ublk = bx&63): 16 units x 4 gates, full K.
// wave w: gate g = w&3, K-chunk kh = w>>2 (0..3). MFMA 16x16x32 bf16.
//   cell0: hh0 chunk kh*256 (8 MFMA) + x-part chunk kh*128 (4 MFMA)
//   cell1: kh<2 -> ih1 chunk kh*512 ; kh>=2 -> hh1 chunk (kh-2)*512
//   cell2: kh<2 -> ih2 chunk kh*512 ; kh>=2 -> hh2 chunk (kh-2)*512
__global__ __launch_bounds__(1024) void k_rec_step(
    const ushort* __restrict__ wsb,
    const float* __restrict__ bih0, const float* __restrict__ bhh0,
    const float* __restrict__ bih1, const float* __restrict__ bhh1,
    const float* __restrict__ bih2, const float* __restrict__ bhh2,
    ushort* __restrict__ h0r, ushort* __restrict__ h1r,
    ushort* __restrict__ h2b, float* __restrict__ cbuf,
    const int* __restrict__ dec_in, int d)
{
    __shared__ float lds[4][4][16][16];   // [kh][g][b][j16] = 16 KB
    int cell = blockIdx.x >> 6, ublk = blockIdx.x & 63;
    int t = d - cell;
    if (t < 0 || t >= TT) return;
    int tid = threadIdx.x;
    int w = tid >> 6, g = w & 3, kh = w >> 2;
    int lane = tid & 63, l15 = lane & 15, quad = lane >> 4;
    int n = g * 1024 + ublk * 16 + l15;

    f32x4 acc = {0.f, 0.f, 0.f, 0.f};

    if (cell == 0) {
        const ushort* Ab = h0r + ((d - 1) & 3) * 16384;
        const ushort* Wb = wsb + OFF_WB;                 // Whh0
        const ushort* ap = Ab + l15 * 1024 + kh * 256 + quad * 8;
        const ushort* wp = Wb + (size_t)n * 1024 + kh * 256 + quad * 8;
        #pragma unroll 4
        for (int k0 = 0; k0 < 256; k0 += 32)
            acc = __builtin_amdgcn_mfma_f32_16x16x32_bf16(
                *(const bf16x8*)(ap + k0), *(const bf16x8*)(wp + k0), acc, 0, 0, 0);
        int tok = dec_in[d * 16 + l15];
        const ushort* ap2 = wsb + OFF_EMBB + (size_t)tok * 512 + kh * 128 + quad * 8;
        const ushort* wp2 = wsb + OFF_WX + (size_t)n * 512 + kh * 128 + quad * 8;
        #pragma unroll 4
        for (int k0 = 0; k0 < 128; k0 += 32)
            acc = __builtin_amdgcn_mfma_f32_16x16x32_bf16(
                *(const bf16x8*)(ap2 + k0), *(const bf16x8*)(wp2 + k0), acc, 0, 0, 0);
    } else {
        const ushort* Ab; const ushort* Wb;
        if (cell == 1) {
            if (kh < 2) { Ab = h0r + ((d - 1) & 3) * 16384; Wb = wsb + OFF_WB + 1 * SZ_W1; }
            else        { Ab = h1r + ((d - 2) & 3) * 16384; Wb = wsb + OFF_WB + 2 * SZ_W1; }
        } else {
            if (kh < 2) { Ab = h1r + ((d - 2) & 3) * 16384; Wb = wsb + OFF_WB + 3 * SZ_W1; }
            else        { Ab = h2b + (size_t)(d - 2) * 16384; Wb = wsb + OFF_WB + 4 * SZ_W1; }
        }
        int kst = (kh & 1) * 512;
        const ushort* ap = Ab + l15 * 1024 + kst + quad * 8;
        const ushort* wp = Wb + (size_t)n * 1024 + kst + quad * 8;
        #pragma unroll 4
        for (int k0 = 0; k0 < 512; k0 += 32)
            acc = __builtin_amdgcn_mfma_f32_16x16x32_bf16(
                *(const bf16x8*)(ap + k0), *(const bf16x8*)(wp + k0), acc, 0, 0, 0);
    }

    // C/D layout: col = lane&15 (unit), row = quad*4+reg (batch)
    #pragma unroll
    for (int r = 0; r < 4; r++) lds[kh][g][quad * 4 + r][l15] = acc[r];
    __syncthreads();

    if (tid < 256) {
        int b = tid >> 4, j16 = tid & 15;
        int j = ublk * 16 + j16;
        const float* bi; const float* bh; ushort* hdst;
        if (cell == 0)      { bi = bih0; bh = bhh0; hdst = h0r + (d & 3) * 16384; }
        else if (cell == 1) { bi = bih1; bh = bhh1; hdst = h1r + ((d - 1) & 3) * 16384; }
        else                { bi = bih2; bh = bhh2; hdst = h2b + (size_t)(d - 1) * 16384; }
        float gv[4];
        #pragma unroll
        for (int gi = 0; gi < 4; gi++)
            gv[gi] = lds[0][gi][b][j16] + lds[1][gi][b][j16]
                   + lds[2][gi][b][j16] + lds[3][gi][b][j16]
                   + bi[gi * 1024 + j] + bh[gi * 1024 + j];
        float ig = sigm(gv[0]), fg = sigm(gv[1]);
        float gg = tanhf(gv[2]), og = sigm(gv[3]);
        float* cp = cbuf + (size_t)(cell * 16 + b) * 1024 + j;
        float c = fg * (*cp) + ig * gg;
        *cp = c;
        hdst[b * 1024 + j] = f2bf(og * tanhf(c));
    }
}

// ---------------------------------------------------------------------------
// bf16 MFMA NT-GEMM: C[M,N] (+)= A @ B^T, all bf16.  64x64 tile, 4 waves;
// wave w computes rows [w*16, w*16+16) x 64 cols. Direct fragment loads.
// A row gather via aIdx (nullable). Batched via blockIdx.z strides.
__global__ __launch_bounds__(256) void k_gemm_bb(
    const ushort* __restrict__ A, int lda, long sA, const int* __restrict__ aIdx,
    const ushort* __restrict__ B, int ldb, long sB,
    ushort* __restrict__ C, int ldc, long sC,
    int M, int K, int accum)
{
    int z = blockIdx.z;
    const ushort* Ab = A + (size_t)z * sA;
    const ushort* Bb = B + (size_t)z * sB;
    ushort* Cb = C + (size_t)z * sC;
    int m0 = blockIdx.y * 64, n0 = blockIdx.x * 64;
    int tid = threadIdx.x, w = tid >> 6, lane = tid & 63;
    int l15 = lane & 15, quad = lane >> 4;
    int am = m0 + w * 16 + l15;
    int ar = (am < M) ? (aIdx ? aIdx[am] : am) : (aIdx ? aIdx[0] : 0);
    const ushort* ap = Ab + (size_t)ar * lda + quad * 8;
    const ushort* bp = Bb + (size_t)(n0 + l15) * ldb + quad * 8;
    f32x4 acc[4] = {{0.f,0.f,0.f,0.f},{0.f,0.f,0.f,0.f},{0.f,0.f,0.f,0.f},{0.f,0.f,0.f,0.f}};
    for (int k0 = 0; k0 < K; k0 += 32) {
        bf16x8 af = *(const bf16x8*)(ap + k0);
        #pragma unroll
        for (int j = 0; j < 4; j++) {
            bf16x8 bfb = *(const bf16x8*)(bp + (size_t)j * 16 * ldb + k0);
            acc[j] = __builtin_amdgcn_mfma_f32_16x16x32_bf16(af, bfb, acc[j], 0, 0, 0);
        }
    }
    #pragma unroll
    for (int j = 0; j < 4; j++)
        #pragma unroll
        for (int r = 0; r < 4; r++) {
            int row = m0 + w * 16 + quad * 4 + r;
            if (row < M) {
                ushort* cp = Cb + (size_t)row * ldc + n0 + j * 16 + l15;
                float v = acc[j][r];
                if (accum) v += bf2f(*cp);
                *cp = f2bf(v);
            }
        }
}

// ---------------------------------------------------------------------------
__global__ __launch_bounds__(256) void k_softmax_b(ushort* __restrict__ sc)
{
    __shared__ float red[4];
    ushort* p = sc + (size_t)blockIdx.x * 512;
    int tid = threadIdx.x;
    float a = bf2f(p[tid]), b = bf2f(p[tid + 256]);
    float m = fmaxf(a, b);
    for (int o = 32; o; o >>= 1) m = fmaxf(m, __shfl_xor(m, o, 64));
    if ((tid & 63) == 0) red[tid >> 6] = m;
    __syncthreads();
    m = fmaxf(fmaxf(red[0], red[1]), fmaxf(red[2], red[3]));
    __syncthreads();
    float ea = __expf(a - m), eb = __expf(b - m);
    float s = ea + eb;
    for (int o = 32; o; o >>= 1) s += __shfl_xor(s, o, 64);
    if ((tid & 63) == 0) red[tid >> 6] = s;
    __syncthreads();
    s = red[0] + red[1] + red[2] + red[3];
    float inv = 1.f / s;
    p[tid] = f2bf(ea * inv);
    p[tid + 256] = f2bf(eb * inv);
}

// ---------------------------------------------------------------------------
__global__ __launch_bounds__(256) void k_tanh_bias_b(ushort* __restrict__ hid,
                                                     const float* __restrict__ b1)
{
    size_t i = (size_t)blockIdx.x * 256 + threadIdx.x;
    hid[i] = f2bf(tanhf(bf2f(hid[i]) + b1[i & 1023]));
}

// ---------------------------------------------------------------------------
__global__ __launch_bounds__(256) void k_loss_b(const ushort* __restrict__ logits,
                                                const float* __restrict__ b2,
                                                const int* __restrict__ dec_out_m,
                                                float* __restrict__ out)
{
    __shared__ float red[4];
    int m = blockIdx.x;
    const ushort* p = logits + (size_t)m * 1024;
    int tid = threadIdx.x;
    float v0 = bf2f(p[tid]) + b2[tid];
    float v1 = bf2f(p[tid + 256]) + b2[tid + 256];
    float v2 = bf2f(p[tid + 512]) + b2[tid + 512];
    float v3 = bf2f(p[tid + 768]) + b2[tid + 768];
    float mx = fmaxf(fmaxf(v0, v1), fmaxf(v2, v3));
    for (int o = 32; o; o >>= 1) mx = fmaxf(mx, __shfl_xor(mx, o, 64));
    if ((tid & 63) == 0) red[tid >> 6] = mx;
    __syncthreads();
    mx = fmaxf(fmaxf(red[0], red[1]), fmaxf(red[2], red[3]));
    __syncthreads();
    float s = __expf(v0 - mx) + __expf(v1 - mx) + __expf(v2 - mx) + __expf(v3 - mx);
    for (int o = 32; o; o >>= 1) s += __shfl_xor(s, o, 64);
    if ((tid & 63) == 0) red[tid >> 6] = s;
    __syncthreads();
    if (tid == 0) {
        float ssum = red[0] + red[1] + red[2] + red[3];
        int tgt = dec_out_m[m];
        float tv = bf2f(p[tgt]) + b2[tgt];
        atomicAdd(out, (mx + logf(ssum) - tv) * (1.0f / 4112.0f));
    }
}

// ---------------------------------------------------------------------------
extern "C" void kernel_launch(void* const* d_in, const int* in_sizes, int n_in,
                              void* d_out, int out_size, void* d_ws, size_t ws_size,
                              hipStream_t stream)
{
    const int*   tokens = (const int*)d_in[0];
    const float* enc    = (const float*)d_in[1];
    const float* emb    = (const float*)d_in[2];
    const float* Wih0   = (const float*)d_in[3];
    const float* Whh0   = (const float*)d_in[4];
    const float* bih0   = (const float*)d_in[5];
    const float* bhh0   = (const float*)d_in[6];
    const float* Wih1   = (const float*)d_in[7];
    const float* Whh1   = (const float*)d_in[8];
    const float* bih1   = (const float*)d_in[9];
    const float* bhh1   = (const float*)d_in[10];
    const float* Wih2   = (const float*)d_in[11];
    const float* Whh2   = (const float*)d_in[12];
    const float* bih2   = (const float*)d_in[13];
    const float* bhh2   = (const float*)d_in[14];
    const float* W1     = (const float*)d_in[15];
    const float* b1     = (const float*)d_in[16];
    const float* W2     = (const float*)d_in[17];
    const float* b2     = (const float*)d_in[18];

    float* out = (float*)d_out;
    if (ws_size < TOTAL_BYTES) { k_fail<<<1, 1, 0, stream>>>(out); return; }

    ushort* wsb  = (ushort*)d_ws;
    ushort* h2b  = wsb + OFF_H2B;
    ushort* h0r  = wsb + OFF_H0R;
    ushort* h1r  = wsb + OFF_H1R;
    ushort* sc   = wsb + OFF_SC;
    ushort* ctx  = wsb + OFF_CTX;
    ushort* hid  = wsb + OFF_HID;
    ushort* lg   = wsb + OFF_LG;
    ushort* encB = wsb + OFF_ENCB;
    ushort* encT = wsb + OFF_ENCT;
    ushort* W1b  = wsb + OFF_W1B;
    ushort* W2b  = wsb + OFF_W2B;
    float*  cbuf = (float*)((char*)d_ws + OFF_CB_BYTES);
    int* dec_in  = (int*)((char*)d_ws + OFF_INT_BYTES);
    int* dec_out = dec_in + 4112;
    int* hsrow   = dec_in + 8224;

    k_init<<<256, 256, 0, stream>>>(tokens, wsb, out);
    k_cvt_pre<<<dim3(2048, 7), 256, 0, stream>>>(Whh0, Wih1, Whh1, Wih2, Whh2,
                                                 Wih0, emb, wsb);

    for (int d = 0; d < 259; d++) {
        k_rec_step<<<192, 1024, 0, stream>>>(wsb, bih0, bhh0, bih1, bhh1,
                                             bih2, bhh2, h0r, h1r, h2b, cbuf,
                                             dec_in, d);
    }

    // epilogue conversions (alias over recurrence weight region)
    k_cvt_flat<<<4096, 256, 0, stream>>>(enc, encB);
    k_enc_t<<<dim3(16, 32, 16), 256, 0, stream>>>(enc, encT);
    k_cvt_flat<<<1024, 256, 0, stream>>>(W1, W1b);
    k_cvt_flat<<<512, 256, 0, stream>>>(W2, W2b);

    // scores[b][t][s] = h2(t) . enc[b,s]
    k_gemm_bb<<<dim3(8, 5, 16), 256, 0, stream>>>(h2b + 16384, 16384, 1024, nullptr,
                                                  encB, 1024, 524288,
                                                  sc, 512, 131584, TT, 1024, 0);
    k_softmax_b<<<4112, 256, 0, stream>>>(sc);
    // ctx[b][t][h] = attn . encT[b][h]
    k_gemm_bb<<<dim3(16, 5, 16), 256, 0, stream>>>(sc, 512, 131584, nullptr,
                                                   encT, 512, 524288,
                                                   ctx, 1024, 263168, TT, 512, 0);
    // hidden = hs @ W1[:, :1024]^T + ctx @ W1[:, 1024:]^T, then tanh(+b1)
    k_gemm_bb<<<dim3(16, 65, 1), 256, 0, stream>>>(h2b, 1024, 0, hsrow,
                                                   W1b, 2048, 0,
                                                   hid, 1024, 0, BT, 1024, 0);
    k_gemm_bb<<<dim3(16, 65, 1), 256, 0, stream>>>(ctx, 1024, 0, nullptr,
                                                   W1b + 1024, 2048, 0,
                                                   hid, 1024, 0, BT, 1024, 1);
    k_tanh_bias_b<<<16448, 256, 0, stream>>>(hid, b1);
    // logits = hidden @ W2^T ; loss
    k_gemm_bb<<<dim3(16, 65, 1), 256, 0, stream>>>(hid, 1024, 0, nullptr,
                                                   W2b, 1024, 0,
                                                   lg, 1024, 0, BT, 1024, 0);
    k_loss_b<<<4112, 256, 0, stream>>>(lg, b2, dec_out, out);
}